// Round 6
// baseline (46.714 us; speedup 1.0000x reference)
//
#include <hip/hip_runtime.h>

#define NB 8
#define NS 2048
#define ND 512
#define NKD 64
#define NM (NB*NS)

typedef _Float16 f16x8 __attribute__((ext_vector_type(8)));
typedef float f32x4 __attribute__((ext_vector_type(4)));

// ---------------------------------------------------------------------------
// Workspace layout (f16):
//   wfrag : 20480 f16x8 (327,680 B)  -- W B-fragments, 5 projections
//   qkri  : [p in 0..3][m in 0..NM)[64] f16   (8,388,608 B)  p: qr,qi,kr,ki
//   vT    : [b][d in 0..64)[s in 0..NS) f16   (2,097,152 B)  transposed V
// ---------------------------------------------------------------------------

// Kernel 0: W -> f16 B-fragment order for mfma_f32_16x16x32_f16 (unchanged).
__global__ __launch_bounds__(256) void wprep_kernel(
    const float* __restrict__ w0, const float* __restrict__ w1,
    const float* __restrict__ w2, const float* __restrict__ w3,
    const float* __restrict__ w4,
    f16x8* __restrict__ wfrag)
{
    const int t = blockIdx.x * 256 + threadIdx.x;     // 0..20479
    const int p    = t >> 12;
    const int nf   = (t >> 10) & 3;
    const int kt   = (t >> 6) & 15;
    const int lane = t & 63;
    const float* __restrict__ W = (p==0)?w0:(p==1)?w1:(p==2)?w2:(p==3)?w3:w4;
    const int n  = nf*16 + (lane & 15);
    const int k0 = kt*32 + (lane >> 4)*8;
    f16x8 v;
    #pragma unroll
    for (int j = 0; j < 8; ++j)
        v[j] = (_Float16)W[(size_t)(k0 + j)*NKD + n];
    wfrag[t] = v;
}

// ---------------------------------------------------------------------------
// Kernel A: FUSED projection GEMM (unchanged from round 5).
// ---------------------------------------------------------------------------
__global__ __launch_bounds__(256) void proj_mfma(
    const float* __restrict__ x,
    const f16x8* __restrict__ wfrag,
    const float* __restrict__ b0, const float* __restrict__ b1,
    const float* __restrict__ b2, const float* __restrict__ b3,
    const float* __restrict__ b4,
    const float* __restrict__ p0, const float* __restrict__ p1,
    const float* __restrict__ p2, const float* __restrict__ p3,
    _Float16* __restrict__ qkri,
    _Float16* __restrict__ vT)
{
    const int g    = (blockIdx.x * 256 + threadIdx.x) >> 6;  // m-tile 0..1023
    const int lane = threadIdx.x & 63;
    const int m0   = g * 16;

    const int row = m0 + (lane & 15);
    const int kb  = (lane >> 4) * 8;
    const float* __restrict__ xrow = x + (size_t)row * ND + kb;
    const f16x8* __restrict__ wf   = wfrag + lane;

    f32x4 acc[5][4];
    #pragma unroll
    for (int p = 0; p < 5; ++p)
        #pragma unroll
        for (int nf = 0; nf < 4; ++nf) acc[p][nf] = (f32x4){0.f,0.f,0.f,0.f};

    for (int kt = 0; kt < 16; ++kt) {
        float4 xa = *(const float4*)(xrow + kt*32);
        float4 xb = *(const float4*)(xrow + kt*32 + 4);
        f16x8 a;
        a[0]=(_Float16)xa.x; a[1]=(_Float16)xa.y;
        a[2]=(_Float16)xa.z; a[3]=(_Float16)xa.w;
        a[4]=(_Float16)xb.x; a[5]=(_Float16)xb.y;
        a[6]=(_Float16)xb.z; a[7]=(_Float16)xb.w;
        #pragma unroll
        for (int p = 0; p < 5; ++p)
            #pragma unroll
            for (int nf = 0; nf < 4; ++nf) {
                f16x8 b = wf[(p*4 + nf)*1024 + kt*64];
                acc[p][nf] = __builtin_amdgcn_mfma_f32_16x16x32_f16(a, b, acc[p][nf], 0, 0, 0);
            }
    }

    const float* biases[5] = {b0, b1, b2, b3, b4};
    const float* poss[4]   = {p0, p1, p2, p3};

    const int col   = lane & 15;
    const int rbase = (lane >> 4) << 2;
    const int bidx  = m0 >> 11;               // batch (tile never crosses)

    #pragma unroll
    for (int p = 0; p < 4; ++p) {
        _Float16* ob = qkri + ((size_t)p*NM + m0) * NKD;
        #pragma unroll
        for (int nf = 0; nf < 4; ++nf) {
            const int c = nf*16 + col;
            const float bb = biases[p][c];
            #pragma unroll
            for (int r = 0; r < 4; ++r) {
                const int mm = rbase + r;
                const int s  = (m0 + mm) & (NS - 1);
                float t = acc[p][nf][r] + bb;
                if (p < 2) t = t * 0.125f + poss[p][s*NKD + c];
                else       t = t + poss[p][s*NKD + c];
                ob[(size_t)mm*NKD + c] = (_Float16)t;
            }
        }
    }
    {
        _Float16* vb = vT + (size_t)bidx*NKD*NS;
        #pragma unroll
        for (int nf = 0; nf < 4; ++nf) {
            const int c = nf*16 + col;
            const float bb = b4[c];
            #pragma unroll
            for (int r = 0; r < 4; ++r) {
                const int s = (m0 + rbase + r) & (NS - 1);
                vb[(size_t)c*NS + s] = (_Float16)(acc[4][nf][r] + bb);
            }
        }
    }
}

// ---------------------------------------------------------------------------
// Kernel B: banded causal attention, ONE WAVE PER 16-QUERY TILE.
// grid = (NS/16, NB) = 1024 blocks x 64 thr.  No K/V staging, no block
// barriers: K/V B-fragments are 16B gathers straight from L2.  Only P
// round-trips through a tiny per-block LDS buffer (6400 B).
// Window = 9 key-tiles: keys [i0-128, i0+15]; PV pads keys 144..159 w/ 0.
// ---------------------------------------------------------------------------
#define PSTR 200              /* f16 stride for P rows (400 B, 16B-aligned) */

__global__ __launch_bounds__(64) void attn_mfma(
    const _Float16* __restrict__ qkri,
    const _Float16* __restrict__ vT,
    const float* __restrict__ temp,
    float* __restrict__ out)
{
    __shared__ _Float16 pl[16 * PSTR];          // 6400 B

    const int lane = threadIdx.x;               // 0..63
    const int i0   = blockIdx.x * 16;
    const int b    = blockIdx.y;
    const int jb   = i0 - 128;                  // global key of window slot 0

    const _Float16* __restrict__ qr_g = qkri + ((size_t)0*NM + (size_t)b*NS)*NKD;
    const _Float16* __restrict__ qi_g = qkri + ((size_t)1*NM + (size_t)b*NS)*NKD;
    const _Float16* __restrict__ kr_g = qkri + ((size_t)2*NM + (size_t)b*NS)*NKD;
    const _Float16* __restrict__ ki_g = qkri + ((size_t)3*NM + (size_t)b*NS)*NKD;
    const _Float16* __restrict__ vT_b = vT + (size_t)b*NKD*NS;

    // ---- Q fragments (imag negated: qr·kr − qi·ki) ----
    const int qrow = i0 + (lane & 15);
    const int d0   = (lane >> 4) * 8;
    f16x8 aqr[2], aqi[2];
    #pragma unroll
    for (int kt = 0; kt < 2; ++kt) {
        aqr[kt] = *(const f16x8*)&qr_g[(size_t)qrow*NKD + kt*32 + d0];
        f16x8 qi8 = *(const f16x8*)&qi_g[(size_t)qrow*NKD + kt*32 + d0];
        aqi[kt] = -qi8;
    }

    // ---- QK^T: 9 tiles x 4 MFMA, B-frags direct from global (L2) ----
    const f16x8 zf = {};
    f32x4 st[9];
    #pragma unroll
    for (int t = 0; t < 9; ++t) {
        const int row = jb + 16*t + (lane & 15);
        const bool ok = (row >= 0);
        const _Float16* krp = kr_g + (size_t)row*NKD + d0;
        const _Float16* kip = ki_g + (size_t)row*NKD + d0;
        f16x8 bkr0 = ok ? *(const f16x8*)(krp)      : zf;
        f16x8 bkr1 = ok ? *(const f16x8*)(krp + 32) : zf;
        f16x8 bki0 = ok ? *(const f16x8*)(kip)      : zf;
        f16x8 bki1 = ok ? *(const f16x8*)(kip + 32) : zf;
        f32x4 acc = (f32x4){0.f,0.f,0.f,0.f};
        acc = __builtin_amdgcn_mfma_f32_16x16x32_f16(aqr[0], bkr0, acc, 0,0,0);
        acc = __builtin_amdgcn_mfma_f32_16x16x32_f16(aqr[1], bkr1, acc, 0,0,0);
        acc = __builtin_amdgcn_mfma_f32_16x16x32_f16(aqi[0], bki0, acc, 0,0,0);
        acc = __builtin_amdgcn_mfma_f32_16x16x32_f16(aqi[1], bki1, acc, 0,0,0);
        st[t] = acc;
    }

    // ---- mask + scale, row max/sum over the 16 col-lanes ----
    const float sT  = 0.125f * temp[0];
    const int col   = lane & 15;
    const int qg4   = (lane >> 4) * 4;
    const int jrmin = -jb;                      // j_global >= 0
    float mx[4] = {-3e38f, -3e38f, -3e38f, -3e38f};
    #pragma unroll
    for (int t = 0; t < 9; ++t) {
        const int jr = 16*t + col;
        #pragma unroll
        for (int r = 0; r < 4; ++r) {
            const int row16 = qg4 + r;          // valid jj: [row16, row16+128]
            const bool ok = (jr >= row16) && (jr <= 128 + row16) && (jr >= jrmin);
            const float s = ok ? st[t][r]*sT : -1e30f;
            st[t][r] = s;
            mx[r] = fmaxf(mx[r], s);
        }
    }
    #pragma unroll
    for (int off = 1; off < 16; off <<= 1)
        #pragma unroll
        for (int r = 0; r < 4; ++r)
            mx[r] = fmaxf(mx[r], __shfl_xor(mx[r], off, 16));

    float sum[4] = {0.f, 0.f, 0.f, 0.f};
    #pragma unroll
    for (int t = 0; t < 9; ++t)
        #pragma unroll
        for (int r = 0; r < 4; ++r) {
            const float e = __expf(st[t][r] - mx[r]);
            st[t][r] = e;
            sum[r] += e;
        }
    #pragma unroll
    for (int off = 1; off < 16; off <<= 1)
        #pragma unroll
        for (int r = 0; r < 4; ++r)
            sum[r] += __shfl_xor(sum[r], off, 16);
    float inv[4];
    #pragma unroll
    for (int r = 0; r < 4; ++r) inv[r] = 1.0f / sum[r];

    // ---- write P (f16) to LDS in A-frag layout; zero pad keys 144..159 ----
    #pragma unroll
    for (int t = 0; t < 9; ++t) {
        const int jr = 16*t + col;
        #pragma unroll
        for (int r = 0; r < 4; ++r)
            pl[(qg4 + r)*PSTR + jr] = (_Float16)(st[t][r] * inv[r]);
    }
    #pragma unroll
    for (int r = 0; r < 4; ++r)
        pl[(qg4 + r)*PSTR + 144 + col] = (_Float16)0.f;
    __syncthreads();                            // single-wave block: just waitcnt

    // ---- PV: 5 k-steps x 4 n-tiles; V B-frags direct from vT (L2) ----
    f32x4 oacc[4];
    #pragma unroll
    for (int nf = 0; nf < 4; ++nf) oacc[nf] = (f32x4){0.f,0.f,0.f,0.f};
    const _Float16* pa = pl + (lane & 15)*PSTR + (lane >> 4)*8;
    #pragma unroll
    for (int kt = 0; kt < 5; ++kt) {
        f16x8 a = *(const f16x8*)(pa + kt*32);
        const int k0 = jb + kt*32 + (lane >> 4)*8;   // multiple of 8
        const bool okv = (k0 >= 0);
        #pragma unroll
        for (int nf = 0; nf < 4; ++nf) {
            const int d = nf*16 + (lane & 15);
            f16x8 bv = okv ? *(const f16x8*)&vT_b[(size_t)d*NS + k0] : zf;
            oacc[nf] = __builtin_amdgcn_mfma_f32_16x16x32_f16(a, bv, oacc[nf], 0,0,0);
        }
    }

    // ---- epilogue ----
    float* ob = out + ((size_t)b*NS + i0)*NKD;
    #pragma unroll
    for (int nf = 0; nf < 4; ++nf)
        #pragma unroll
        for (int r = 0; r < 4; ++r)
            ob[(size_t)(qg4 + r)*NKD + nf*16 + col] = oacc[nf][r];
}

// ---------------------------------------------------------------------------
extern "C" void kernel_launch(void* const* d_in, const int* in_sizes, int n_in,
                              void* d_out, int out_size, void* d_ws, size_t ws_size,
                              hipStream_t stream)
{
    const float* x    = (const float*)d_in[0];
    const float* w0   = (const float*)d_in[1];
    const float* b0   = (const float*)d_in[2];
    const float* w1   = (const float*)d_in[3];
    const float* b1   = (const float*)d_in[4];
    const float* w2   = (const float*)d_in[5];
    const float* b2   = (const float*)d_in[6];
    const float* w3   = (const float*)d_in[7];
    const float* b3   = (const float*)d_in[8];
    const float* w4   = (const float*)d_in[9];
    const float* b4   = (const float*)d_in[10];
    const float* p0   = (const float*)d_in[11];
    const float* p1   = (const float*)d_in[12];
    const float* p2   = (const float*)d_in[13];
    const float* p3   = (const float*)d_in[14];
    const float* temp = (const float*)d_in[15];

    char* ws = (char*)d_ws;
    f16x8*    wfrag = (f16x8*)ws;                              // 327,680 B
    _Float16* qkri  = (_Float16*)(ws + 327680);                // 8,388,608 B
    _Float16* vT    = (_Float16*)(ws + 327680 + 8388608);      // 2,097,152 B

    wprep_kernel<<<80, 256, 0, stream>>>(w0, w1, w2, w3, w4, wfrag);

    proj_mfma<<<256, 256, 0, stream>>>(x, wfrag,
                                       b0, b1, b2, b3, b4,
                                       p0, p1, p2, p3, qkri, vT);

    dim3 gB(NS/16, NB);
    attn_mfma<<<gB, 64, 0, stream>>>(qkri, vT, temp, (float*)d_out);
}

// Round 10
// 43.772 us; speedup vs baseline: 1.0672x; 1.0672x over previous
//
#include <hip/hip_runtime.h>

#define NB 8
#define NS 2048
#define ND 512
#define NKD 64
#define NM (NB*NS)

typedef _Float16 f16x8 __attribute__((ext_vector_type(8)));
typedef float f32x4 __attribute__((ext_vector_type(4)));

// ---------------------------------------------------------------------------
// Workspace layout (f16):
//   wfrag : 20480 f16x8 (327,680 B)  -- W B-fragments, 5 projections
//   qkri  : [p in 0..3][m in 0..NM)[64] f16   (8,388,608 B)  p: qr,qi,kr,ki
//   vT    : [b][d in 0..64)[s in 0..NS) f16   (2,097,152 B)  transposed V
// ---------------------------------------------------------------------------

// Kernel 0: W -> f16 B-fragment order for mfma_f32_16x16x32_f16 (unchanged).
__global__ __launch_bounds__(256) void wprep_kernel(
    const float* __restrict__ w0, const float* __restrict__ w1,
    const float* __restrict__ w2, const float* __restrict__ w3,
    const float* __restrict__ w4,
    f16x8* __restrict__ wfrag)
{
    const int t = blockIdx.x * 256 + threadIdx.x;     // 0..20479
    const int p    = t >> 12;
    const int nf   = (t >> 10) & 3;
    const int kt   = (t >> 6) & 15;
    const int lane = t & 63;
    const float* __restrict__ W = (p==0)?w0:(p==1)?w1:(p==2)?w2:(p==3)?w3:w4;
    const int n  = nf*16 + (lane & 15);
    const int k0 = kt*32 + (lane >> 4)*8;
    f16x8 v;
    #pragma unroll
    for (int j = 0; j < 8; ++j)
        v[j] = (_Float16)W[(size_t)(k0 + j)*NKD + n];
    wfrag[t] = v;
}

// ---------------------------------------------------------------------------
// Kernel A: FUSED projection GEMM (unchanged from round 5).
// ---------------------------------------------------------------------------
__global__ __launch_bounds__(256) void proj_mfma(
    const float* __restrict__ x,
    const f16x8* __restrict__ wfrag,
    const float* __restrict__ b0, const float* __restrict__ b1,
    const float* __restrict__ b2, const float* __restrict__ b3,
    const float* __restrict__ b4,
    const float* __restrict__ p0, const float* __restrict__ p1,
    const float* __restrict__ p2, const float* __restrict__ p3,
    _Float16* __restrict__ qkri,
    _Float16* __restrict__ vT)
{
    const int g    = (blockIdx.x * 256 + threadIdx.x) >> 6;  // m-tile 0..1023
    const int lane = threadIdx.x & 63;
    const int m0   = g * 16;

    const int row = m0 + (lane & 15);
    const int kb  = (lane >> 4) * 8;
    const float* __restrict__ xrow = x + (size_t)row * ND + kb;
    const f16x8* __restrict__ wf   = wfrag + lane;

    f32x4 acc[5][4];
    #pragma unroll
    for (int p = 0; p < 5; ++p)
        #pragma unroll
        for (int nf = 0; nf < 4; ++nf) acc[p][nf] = (f32x4){0.f,0.f,0.f,0.f};

    for (int kt = 0; kt < 16; ++kt) {
        float4 xa = *(const float4*)(xrow + kt*32);
        float4 xb = *(const float4*)(xrow + kt*32 + 4);
        f16x8 a;
        a[0]=(_Float16)xa.x; a[1]=(_Float16)xa.y;
        a[2]=(_Float16)xa.z; a[3]=(_Float16)xa.w;
        a[4]=(_Float16)xb.x; a[5]=(_Float16)xb.y;
        a[6]=(_Float16)xb.z; a[7]=(_Float16)xb.w;
        #pragma unroll
        for (int p = 0; p < 5; ++p)
            #pragma unroll
            for (int nf = 0; nf < 4; ++nf) {
                f16x8 b = wf[(p*4 + nf)*1024 + kt*64];
                acc[p][nf] = __builtin_amdgcn_mfma_f32_16x16x32_f16(a, b, acc[p][nf], 0, 0, 0);
            }
    }

    const float* biases[5] = {b0, b1, b2, b3, b4};
    const float* poss[4]   = {p0, p1, p2, p3};

    const int col   = lane & 15;
    const int rbase = (lane >> 4) << 2;
    const int bidx  = m0 >> 11;               // batch (tile never crosses)

    #pragma unroll
    for (int p = 0; p < 4; ++p) {
        _Float16* ob = qkri + ((size_t)p*NM + m0) * NKD;
        #pragma unroll
        for (int nf = 0; nf < 4; ++nf) {
            const int c = nf*16 + col;
            const float bb = biases[p][c];
            #pragma unroll
            for (int r = 0; r < 4; ++r) {
                const int mm = rbase + r;
                const int s  = (m0 + mm) & (NS - 1);
                float t = acc[p][nf][r] + bb;
                if (p < 2) t = t * 0.125f + poss[p][s*NKD + c];
                else       t = t + poss[p][s*NKD + c];
                ob[(size_t)mm*NKD + c] = (_Float16)t;
            }
        }
    }
    {
        _Float16* vb = vT + (size_t)bidx*NKD*NS;
        #pragma unroll
        for (int nf = 0; nf < 4; ++nf) {
            const int c = nf*16 + col;
            const float bb = b4[c];
            #pragma unroll
            for (int r = 0; r < 4; ++r) {
                const int s = (m0 + rbase + r) & (NS - 1);
                vb[(size_t)c*NS + s] = (_Float16)(acc[4][nf][r] + bb);
            }
        }
    }
}

// ---------------------------------------------------------------------------
// Kernel B: banded causal attention, SHARED-SCORE key split.
// grid = (NS/16, NB) = 1024 blocks x 256 thr (4 waves), 16 waves/CU.
// Phase 1: wave w computes QK^T+mask for its OWN tiles (w0: t0-2 + pad-slots,
//   else t 2w+1..2w+2) and writes masked f32 scores to shared scf[16][164].
// Phase 2: per-lane softmax stats from scf (4-lane shfl reduce), PV A-frag
//   rebuilt in registers (no P LDS round-trip), wave w does PV k-step w
//   (w0 also k-step 4), waves 1-3 publish O partials, w0 sums + stores.
// ---------------------------------------------------------------------------
#define SST 164    /* f32 score stride: 164 mod 32 = 4 -> 2-way banks */
#define OST 68     /* f32 O-partial stride */

__global__ __launch_bounds__(256) void attn_mfma(
    const _Float16* __restrict__ qkri,
    const _Float16* __restrict__ vT,
    const float* __restrict__ temp,
    float* __restrict__ out)
{
    __shared__ __align__(16) float scf[16*SST];      // 10,496 B
    __shared__ __align__(16) float olds[3][16*OST];  // 13,056 B

    const int tid  = threadIdx.x;
    const int w    = tid >> 6;
    const int lane = tid & 63;
    const int i0   = blockIdx.x * 16;
    const int b    = blockIdx.y;
    const int jb   = i0 - 128;              // global key of window slot 0

    const _Float16* __restrict__ qr_g = qkri + ((size_t)0*NM + (size_t)b*NS)*NKD;
    const _Float16* __restrict__ qi_g = qkri + ((size_t)1*NM + (size_t)b*NS)*NKD;
    const _Float16* __restrict__ kr_g = qkri + ((size_t)2*NM + (size_t)b*NS)*NKD;
    const _Float16* __restrict__ ki_g = qkri + ((size_t)3*NM + (size_t)b*NS)*NKD;
    const _Float16* __restrict__ vT_b = vT + (size_t)b*NKD*NS;

    const f16x8 zf = {};
    const int col  = lane & 15;
    const int seg  = lane >> 4;             // 0..3
    const int qg4  = seg * 4;

    // ---- Q fragments (imag negated: qr·kr − qi·ki) — R6 verbatim ----
    const int qrow = i0 + col;
    const int d0   = seg * 8;
    f16x8 aqr[2], aqi[2];
    #pragma unroll
    for (int kt = 0; kt < 2; ++kt) {
        aqr[kt] = *(const f16x8*)&qr_g[(size_t)qrow*NKD + kt*32 + d0];
        f16x8 qi8 = *(const f16x8*)&qi_g[(size_t)qrow*NKD + kt*32 + d0];
        aqi[kt] = -qi8;
    }

    // ---- Phase 1: QK^T + mask for owned tiles -> scf (f32 scalar) ----
    const float sT  = 0.125f * temp[0];
    const int jrmin = -jb;                  // j_global >= 0
    const int tA = (w == 0) ? 0 : (2*w + 1);
    const int tB = 2*w + 2;

    for (int t = tA; t <= tB; ++t) {        // 2 or 3 iters, wave-uniform
        const int row = jb + 16*t + col;
        const bool ok = (row >= 0);
        const _Float16* krp = kr_g + (size_t)row*NKD + d0;
        const _Float16* kip = ki_g + (size_t)row*NKD + d0;
        f16x8 bkr0 = ok ? *(const f16x8*)(krp)      : zf;
        f16x8 bkr1 = ok ? *(const f16x8*)(krp + 32) : zf;
        f16x8 bki0 = ok ? *(const f16x8*)(kip)      : zf;
        f16x8 bki1 = ok ? *(const f16x8*)(kip + 32) : zf;
        f32x4 acc = (f32x4){0.f,0.f,0.f,0.f};
        acc = __builtin_amdgcn_mfma_f32_16x16x32_f16(aqr[0], bkr0, acc, 0,0,0);
        acc = __builtin_amdgcn_mfma_f32_16x16x32_f16(aqr[1], bkr1, acc, 0,0,0);
        acc = __builtin_amdgcn_mfma_f32_16x16x32_f16(aqi[0], bki0, acc, 0,0,0);
        acc = __builtin_amdgcn_mfma_f32_16x16x32_f16(aqi[1], bki1, acc, 0,0,0);
        const int jr = 16*t + col;
        #pragma unroll
        for (int r = 0; r < 4; ++r) {
            const int row16 = qg4 + r;      // valid slots: [row16, row16+128]
            const bool okm = (jr >= row16) && (jr <= 128 + row16) && (jr >= jrmin);
            scf[(qg4 + r)*SST + jr] = okm ? acc[r]*sT : -1e30f;
        }
    }
    if (w == 0) {                           // pad slots 144..159
        #pragma unroll
        for (int r = 0; r < 4; ++r)
            scf[(qg4 + r)*SST + 144 + col] = -1e30f;
    }
    __syncthreads();

    // ---- Phase 2: per-lane softmax stats (row q = col, segment seg) ----
    const float* srow = &scf[col*SST + seg*40];
    float4 vv[10];
    float m = -3e38f;
    #pragma unroll
    for (int c = 0; c < 10; ++c) {
        vv[c] = *(const float4*)(srow + 4*c);
        m = fmaxf(m, fmaxf(fmaxf(vv[c].x, vv[c].y), fmaxf(vv[c].z, vv[c].w)));
    }
    m = fmaxf(m, __shfl_xor(m, 16));
    m = fmaxf(m, __shfl_xor(m, 32));
    float l = 0.f;
    #pragma unroll
    for (int c = 0; c < 10; ++c) {
        l += __expf(vv[c].x - m) + __expf(vv[c].y - m)
           + __expf(vv[c].z - m) + __expf(vv[c].w - m);
    }
    l += __shfl_xor(l, 16);
    l += __shfl_xor(l, 32);
    const float inv = 1.0f / l;

    // ---- PV: wave w does k-step w; w0 also k-step 4 ----
    f32x4 oacc[4];
    #pragma unroll
    for (int nf = 0; nf < 4; ++nf) oacc[nf] = (f32x4){0.f,0.f,0.f,0.f};

    #pragma unroll
    for (int pass = 0; pass < 2; ++pass) {
        const int kt = (pass == 0) ? w : 4;
        if (pass == 1 && w != 0) break;     // wave-uniform
        const int sb = 32*kt + seg*8;       // slot base for this lane
        float4 e0 = *(const float4*)&scf[col*SST + sb];
        float4 e1 = *(const float4*)&scf[col*SST + sb + 4];
        f16x8 a;
        a[0] = (_Float16)(__expf(e0.x - m) * inv);
        a[1] = (_Float16)(__expf(e0.y - m) * inv);
        a[2] = (_Float16)(__expf(e0.z - m) * inv);
        a[3] = (_Float16)(__expf(e0.w - m) * inv);
        a[4] = (_Float16)(__expf(e1.x - m) * inv);
        a[5] = (_Float16)(__expf(e1.y - m) * inv);
        a[6] = (_Float16)(__expf(e1.z - m) * inv);
        a[7] = (_Float16)(__expf(e1.w - m) * inv);
        const int k0 = jb + 32*kt + seg*8;  // multiple of 8
        const bool okv = (k0 >= 0) && (k0 <= NS - 8);
        #pragma unroll
        for (int nf = 0; nf < 4; ++nf) {
            const int d = nf*16 + col;
            f16x8 bv = okv ? *(const f16x8*)&vT_b[(size_t)d*NS + k0] : zf;
            oacc[nf] = __builtin_amdgcn_mfma_f32_16x16x32_f16(a, bv, oacc[nf], 0,0,0);
        }
    }

    // ---- publish partials (waves 1-3), combine + store (wave 0) ----
    if (w > 0) {
        #pragma unroll
        for (int nf = 0; nf < 4; ++nf)
            #pragma unroll
            for (int r = 0; r < 4; ++r)
                olds[w-1][(qg4 + r)*OST + nf*16 + col] = oacc[nf][r];
    }
    __syncthreads();
    if (w == 0) {
        float* ob = out + ((size_t)b*NS + i0)*NKD;
        #pragma unroll
        for (int nf = 0; nf < 4; ++nf)
            #pragma unroll
            for (int r = 0; r < 4; ++r) {
                const int idx = (qg4 + r)*OST + nf*16 + col;
                const float v = oacc[nf][r] + olds[0][idx] + olds[1][idx] + olds[2][idx];
                ob[(size_t)(qg4 + r)*NKD + nf*16 + col] = v;
            }
    }
}

// ---------------------------------------------------------------------------
extern "C" void kernel_launch(void* const* d_in, const int* in_sizes, int n_in,
                              void* d_out, int out_size, void* d_ws, size_t ws_size,
                              hipStream_t stream)
{
    const float* x    = (const float*)d_in[0];
    const float* w0   = (const float*)d_in[1];
    const float* b0   = (const float*)d_in[2];
    const float* w1   = (const float*)d_in[3];
    const float* b1   = (const float*)d_in[4];
    const float* w2   = (const float*)d_in[5];
    const float* b2   = (const float*)d_in[6];
    const float* w3   = (const float*)d_in[7];
    const float* b3   = (const float*)d_in[8];
    const float* w4   = (const float*)d_in[9];
    const float* b4   = (const float*)d_in[10];
    const float* p0   = (const float*)d_in[11];
    const float* p1   = (const float*)d_in[12];
    const float* p2   = (const float*)d_in[13];
    const float* p3   = (const float*)d_in[14];
    const float* temp = (const float*)d_in[15];

    char* ws = (char*)d_ws;
    f16x8*    wfrag = (f16x8*)ws;                              // 327,680 B
    _Float16* qkri  = (_Float16*)(ws + 327680);                // 8,388,608 B
    _Float16* vT    = (_Float16*)(ws + 327680 + 8388608);      // 2,097,152 B

    wprep_kernel<<<80, 256, 0, stream>>>(w0, w1, w2, w3, w4, wfrag);

    proj_mfma<<<256, 256, 0, stream>>>(x, wfrag,
                                       b0, b1, b2, b3, b4,
                                       p0, p1, p2, p3, qkri, vT);

    dim3 gB(NS/16, NB);
    attn_mfma<<<gB, 256, 0, stream>>>(qkri, vT, temp, (float*)d_out);
}

// Round 11
// 43.708 us; speedup vs baseline: 1.0688x; 1.0015x over previous
//
#include <hip/hip_runtime.h>

#define NB 8
#define NS 2048
#define ND 512
#define NKD 64
#define NM (NB*NS)

typedef _Float16 f16x8 __attribute__((ext_vector_type(8)));
typedef float f32x4 __attribute__((ext_vector_type(4)));

// ---------------------------------------------------------------------------
// Workspace layout (f16):
//   wfrag : 20480 f16x8 (327,680 B)  -- W B-fragments, 5 projections
//   qkri  : [p in 0..3][m in 0..NM)[64] f16   (8,388,608 B)  p: qr,qi,kr,ki
//   vT    : [b][d in 0..64)[s in 0..NS) f16   (2,097,152 B)  transposed V
// ---------------------------------------------------------------------------

// Kernel 0: W -> f16 B-fragment order for mfma_f32_16x16x32_f16 (unchanged).
__global__ __launch_bounds__(256) void wprep_kernel(
    const float* __restrict__ w0, const float* __restrict__ w1,
    const float* __restrict__ w2, const float* __restrict__ w3,
    const float* __restrict__ w4,
    f16x8* __restrict__ wfrag)
{
    const int t = blockIdx.x * 256 + threadIdx.x;     // 0..20479
    const int p    = t >> 12;
    const int nf   = (t >> 10) & 3;
    const int kt   = (t >> 6) & 15;
    const int lane = t & 63;
    const float* __restrict__ W = (p==0)?w0:(p==1)?w1:(p==2)?w2:(p==3)?w3:w4;
    const int n  = nf*16 + (lane & 15);
    const int k0 = kt*32 + (lane >> 4)*8;
    f16x8 v;
    #pragma unroll
    for (int j = 0; j < 8; ++j)
        v[j] = (_Float16)W[(size_t)(k0 + j)*NKD + n];
    wfrag[t] = v;
}

// ---------------------------------------------------------------------------
// Kernel A: FUSED projection GEMM, restructured for TLP + vector stores.
// grid = 512 blocks x 256 thr (4 waves) = 2048 waves (2/SIMD, was 1/SIMD).
// Block covers 2 m-tiles (32 rows).  Wave (mt_local, half):
//   half 0: p=0,1 (qr,qi) + v nf 0,1     half 1: p=2,3 (kr,ki) + v nf 2,3
// 10 MFMA streams/wave (acc = 40 VGPR), 10 B-frag loads/kt.
// vT epilogue: in-LDS transpose -> 16B/lane contiguous global stores
// (was: 2-byte scalar scatter at 4KB stride).
// ---------------------------------------------------------------------------
__global__ __launch_bounds__(256) void proj_mfma(
    const float* __restrict__ x,
    const f16x8* __restrict__ wfrag,
    const float* __restrict__ b0, const float* __restrict__ b1,
    const float* __restrict__ b2, const float* __restrict__ b3,
    const float* __restrict__ b4,
    const float* __restrict__ p0, const float* __restrict__ p1,
    const float* __restrict__ p2, const float* __restrict__ p3,
    _Float16* __restrict__ qkri,
    _Float16* __restrict__ vT)
{
    __shared__ __align__(16) _Float16 vtile[64][40];   // 5,120 B (32 s-cols used)

    const int w    = threadIdx.x >> 6;
    const int lane = threadIdx.x & 63;
    const int half = w & 1;                    // 0: qr,qi,v01   1: kr,ki,v23
    const int mt   = blockIdx.x*2 + (w >> 1);  // global 16-row m-tile
    const int m0   = mt * 16;

    const int col   = lane & 15;
    const int rbase = (lane >> 4) << 2;

    const float* __restrict__ xrow = x + (size_t)(m0 + col) * ND + (lane >> 4)*8;
    const f16x8* __restrict__ wf   = wfrag + lane;
    const int pa = half * 2;                   // first dense projection

    f32x4 acc[2][4], accv[2];
    #pragma unroll
    for (int pp = 0; pp < 2; ++pp)
        #pragma unroll
        for (int nf = 0; nf < 4; ++nf) acc[pp][nf] = (f32x4){0.f,0.f,0.f,0.f};
    accv[0] = (f32x4){0.f,0.f,0.f,0.f};
    accv[1] = (f32x4){0.f,0.f,0.f,0.f};

    for (int kt = 0; kt < 16; ++kt) {
        float4 xa = *(const float4*)(xrow + kt*32);
        float4 xb = *(const float4*)(xrow + kt*32 + 4);
        f16x8 a;
        a[0]=(_Float16)xa.x; a[1]=(_Float16)xa.y;
        a[2]=(_Float16)xa.z; a[3]=(_Float16)xa.w;
        a[4]=(_Float16)xb.x; a[5]=(_Float16)xb.y;
        a[6]=(_Float16)xb.z; a[7]=(_Float16)xb.w;
        #pragma unroll
        for (int pp = 0; pp < 2; ++pp)
            #pragma unroll
            for (int nf = 0; nf < 4; ++nf) {
                f16x8 b = wf[((pa + pp)*4 + nf)*1024 + kt*64];
                acc[pp][nf] = __builtin_amdgcn_mfma_f32_16x16x32_f16(a, b, acc[pp][nf], 0, 0, 0);
            }
        #pragma unroll
        for (int j = 0; j < 2; ++j) {
            const int nfv = half*2 + j;
            f16x8 b = wf[(16 + nfv)*1024 + kt*64];
            accv[j] = __builtin_amdgcn_mfma_f32_16x16x32_f16(a, b, accv[j], 0, 0, 0);
        }
    }

    const float* biases[5] = {b0, b1, b2, b3, b4};
    const float* poss[4]   = {p0, p1, p2, p3};

    // ---- qr/qi/kr/ki epilogue (2 projections per wave) ----
    #pragma unroll
    for (int pp = 0; pp < 2; ++pp) {
        const int p = pa + pp;
        _Float16* ob = qkri + ((size_t)p*NM + m0) * NKD;
        #pragma unroll
        for (int nf = 0; nf < 4; ++nf) {
            const int c = nf*16 + col;
            const float bb = biases[p][c];
            #pragma unroll
            for (int r = 0; r < 4; ++r) {
                const int mm = rbase + r;
                const int s  = (m0 + mm) & (NS - 1);
                float t = acc[pp][nf][r] + bb;
                if (p < 2) t = t * 0.125f + poss[p][s*NKD + c];
                else       t = t + poss[p][s*NKD + c];
                ob[(size_t)mm*NKD + c] = (_Float16)t;
            }
        }
    }

    // ---- v -> LDS tile (d-major), then vectorized vT stores ----
    #pragma unroll
    for (int j = 0; j < 2; ++j) {
        const int c = (half*2 + j)*16 + col;          // d index 0..63
        const float bb = b4[c];
        #pragma unroll
        for (int r = 0; r < 4; ++r) {
            const int sl = (w >> 1)*16 + rbase + r;   // s-local 0..31
            vtile[c][sl] = (_Float16)(accv[j][r] + bb);
        }
    }
    __syncthreads();
    {
        const int t   = threadIdx.x;
        const int d   = t >> 2;                        // 0..63
        const int sc  = (t & 3) * 8;                   // 0,8,16,24
        const int mblk = blockIdx.x * 32;
        const int bidx = mblk >> 11;
        const int sb   = mblk & (NS - 1);
        f16x8 vv = *(const f16x8*)&vtile[d][sc];
        *(f16x8*)&vT[((size_t)bidx*NKD + d)*NS + sb + sc] = vv;
    }
}

// ---------------------------------------------------------------------------
// Kernel B: banded causal attention, SHARED-SCORE key split (unchanged from
// round 10, which passed).
// ---------------------------------------------------------------------------
#define SST 164    /* f32 score stride: 164 mod 32 = 4 -> 2-way banks */
#define OST 68     /* f32 O-partial stride */

__global__ __launch_bounds__(256) void attn_mfma(
    const _Float16* __restrict__ qkri,
    const _Float16* __restrict__ vT,
    const float* __restrict__ temp,
    float* __restrict__ out)
{
    __shared__ __align__(16) float scf[16*SST];      // 10,496 B
    __shared__ __align__(16) float olds[3][16*OST];  // 13,056 B

    const int tid  = threadIdx.x;
    const int w    = tid >> 6;
    const int lane = tid & 63;
    const int i0   = blockIdx.x * 16;
    const int b    = blockIdx.y;
    const int jb   = i0 - 128;              // global key of window slot 0

    const _Float16* __restrict__ qr_g = qkri + ((size_t)0*NM + (size_t)b*NS)*NKD;
    const _Float16* __restrict__ qi_g = qkri + ((size_t)1*NM + (size_t)b*NS)*NKD;
    const _Float16* __restrict__ kr_g = qkri + ((size_t)2*NM + (size_t)b*NS)*NKD;
    const _Float16* __restrict__ ki_g = qkri + ((size_t)3*NM + (size_t)b*NS)*NKD;
    const _Float16* __restrict__ vT_b = vT + (size_t)b*NKD*NS;

    const f16x8 zf = {};
    const int col  = lane & 15;
    const int seg  = lane >> 4;             // 0..3
    const int qg4  = seg * 4;

    // ---- Q fragments (imag negated: qr·kr − qi·ki) ----
    const int qrow = i0 + col;
    const int d0   = seg * 8;
    f16x8 aqr[2], aqi[2];
    #pragma unroll
    for (int kt = 0; kt < 2; ++kt) {
        aqr[kt] = *(const f16x8*)&qr_g[(size_t)qrow*NKD + kt*32 + d0];
        f16x8 qi8 = *(const f16x8*)&qi_g[(size_t)qrow*NKD + kt*32 + d0];
        aqi[kt] = -qi8;
    }

    // ---- Phase 1: QK^T + mask for owned tiles -> scf (f32 scalar) ----
    const float sT  = 0.125f * temp[0];
    const int jrmin = -jb;                  // j_global >= 0
    const int tA = (w == 0) ? 0 : (2*w + 1);
    const int tB = 2*w + 2;

    for (int t = tA; t <= tB; ++t) {        // 2 or 3 iters, wave-uniform
        const int row = jb + 16*t + col;
        const bool ok = (row >= 0);
        const _Float16* krp = kr_g + (size_t)row*NKD + d0;
        const _Float16* kip = ki_g + (size_t)row*NKD + d0;
        f16x8 bkr0 = ok ? *(const f16x8*)(krp)      : zf;
        f16x8 bkr1 = ok ? *(const f16x8*)(krp + 32) : zf;
        f16x8 bki0 = ok ? *(const f16x8*)(kip)      : zf;
        f16x8 bki1 = ok ? *(const f16x8*)(kip + 32) : zf;
        f32x4 acc = (f32x4){0.f,0.f,0.f,0.f};
        acc = __builtin_amdgcn_mfma_f32_16x16x32_f16(aqr[0], bkr0, acc, 0,0,0);
        acc = __builtin_amdgcn_mfma_f32_16x16x32_f16(aqr[1], bkr1, acc, 0,0,0);
        acc = __builtin_amdgcn_mfma_f32_16x16x32_f16(aqi[0], bki0, acc, 0,0,0);
        acc = __builtin_amdgcn_mfma_f32_16x16x32_f16(aqi[1], bki1, acc, 0,0,0);
        const int jr = 16*t + col;
        #pragma unroll
        for (int r = 0; r < 4; ++r) {
            const int row16 = qg4 + r;      // valid slots: [row16, row16+128]
            const bool okm = (jr >= row16) && (jr <= 128 + row16) && (jr >= jrmin);
            scf[(qg4 + r)*SST + jr] = okm ? acc[r]*sT : -1e30f;
        }
    }
    if (w == 0) {                           // pad slots 144..159
        #pragma unroll
        for (int r = 0; r < 4; ++r)
            scf[(qg4 + r)*SST + 144 + col] = -1e30f;
    }
    __syncthreads();

    // ---- Phase 2: per-lane softmax stats (row q = col, segment seg) ----
    const float* srow = &scf[col*SST + seg*40];
    float4 vv[10];
    float m = -3e38f;
    #pragma unroll
    for (int c = 0; c < 10; ++c) {
        vv[c] = *(const float4*)(srow + 4*c);
        m = fmaxf(m, fmaxf(fmaxf(vv[c].x, vv[c].y), fmaxf(vv[c].z, vv[c].w)));
    }
    m = fmaxf(m, __shfl_xor(m, 16));
    m = fmaxf(m, __shfl_xor(m, 32));
    float l = 0.f;
    #pragma unroll
    for (int c = 0; c < 10; ++c) {
        l += __expf(vv[c].x - m) + __expf(vv[c].y - m)
           + __expf(vv[c].z - m) + __expf(vv[c].w - m);
    }
    l += __shfl_xor(l, 16);
    l += __shfl_xor(l, 32);
    const float inv = 1.0f / l;

    // ---- PV: wave w does k-step w; w0 also k-step 4 ----
    f32x4 oacc[4];
    #pragma unroll
    for (int nf = 0; nf < 4; ++nf) oacc[nf] = (f32x4){0.f,0.f,0.f,0.f};

    #pragma unroll
    for (int pass = 0; pass < 2; ++pass) {
        const int kt = (pass == 0) ? w : 4;
        if (pass == 1 && w != 0) break;     // wave-uniform
        const int sb = 32*kt + seg*8;       // slot base for this lane
        float4 e0 = *(const float4*)&scf[col*SST + sb];
        float4 e1 = *(const float4*)&scf[col*SST + sb + 4];
        f16x8 a;
        a[0] = (_Float16)(__expf(e0.x - m) * inv);
        a[1] = (_Float16)(__expf(e0.y - m) * inv);
        a[2] = (_Float16)(__expf(e0.z - m) * inv);
        a[3] = (_Float16)(__expf(e0.w - m) * inv);
        a[4] = (_Float16)(__expf(e1.x - m) * inv);
        a[5] = (_Float16)(__expf(e1.y - m) * inv);
        a[6] = (_Float16)(__expf(e1.z - m) * inv);
        a[7] = (_Float16)(__expf(e1.w - m) * inv);
        const int k0 = jb + 32*kt + seg*8;  // multiple of 8
        const bool okv = (k0 >= 0) && (k0 <= NS - 8);
        #pragma unroll
        for (int nf = 0; nf < 4; ++nf) {
            const int d = nf*16 + col;
            f16x8 bv = okv ? *(const f16x8*)&vT_b[(size_t)d*NS + k0] : zf;
            oacc[nf] = __builtin_amdgcn_mfma_f32_16x16x32_f16(a, bv, oacc[nf], 0,0,0);
        }
    }

    // ---- publish partials (waves 1-3), combine + store (wave 0) ----
    if (w > 0) {
        #pragma unroll
        for (int nf = 0; nf < 4; ++nf)
            #pragma unroll
            for (int r = 0; r < 4; ++r)
                olds[w-1][(qg4 + r)*OST + nf*16 + col] = oacc[nf][r];
    }
    __syncthreads();
    if (w == 0) {
        float* ob = out + ((size_t)b*NS + i0)*NKD;
        #pragma unroll
        for (int nf = 0; nf < 4; ++nf)
            #pragma unroll
            for (int r = 0; r < 4; ++r) {
                const int idx = (qg4 + r)*OST + nf*16 + col;
                const float v = oacc[nf][r] + olds[0][idx] + olds[1][idx] + olds[2][idx];
                ob[(size_t)(qg4 + r)*NKD + nf*16 + col] = v;
            }
    }
}

// ---------------------------------------------------------------------------
extern "C" void kernel_launch(void* const* d_in, const int* in_sizes, int n_in,
                              void* d_out, int out_size, void* d_ws, size_t ws_size,
                              hipStream_t stream)
{
    const float* x    = (const float*)d_in[0];
    const float* w0   = (const float*)d_in[1];
    const float* b0   = (const float*)d_in[2];
    const float* w1   = (const float*)d_in[3];
    const float* b1   = (const float*)d_in[4];
    const float* w2   = (const float*)d_in[5];
    const float* b2   = (const float*)d_in[6];
    const float* w3   = (const float*)d_in[7];
    const float* b3   = (const float*)d_in[8];
    const float* w4   = (const float*)d_in[9];
    const float* b4   = (const float*)d_in[10];
    const float* p0   = (const float*)d_in[11];
    const float* p1   = (const float*)d_in[12];
    const float* p2   = (const float*)d_in[13];
    const float* p3   = (const float*)d_in[14];
    const float* temp = (const float*)d_in[15];

    char* ws = (char*)d_ws;
    f16x8*    wfrag = (f16x8*)ws;                              // 327,680 B
    _Float16* qkri  = (_Float16*)(ws + 327680);                // 8,388,608 B
    _Float16* vT    = (_Float16*)(ws + 327680 + 8388608);      // 2,097,152 B

    wprep_kernel<<<80, 256, 0, stream>>>(w0, w1, w2, w3, w4, wfrag);

    proj_mfma<<<512, 256, 0, stream>>>(x, wfrag,
                                       b0, b1, b2, b3, b4,
                                       p0, p1, p2, p3, qkri, vT);

    dim3 gB(NS/16, NB);
    attn_mfma<<<gB, 256, 0, stream>>>(qkri, vT, temp, (float*)d_out);
}